// Round 9
// baseline (166.563 us; speedup 1.0000x reference)
//
#include <hip/hip_runtime.h>
#include <math.h>

#define BATCH  32
#define CH     3
#define H      512
#define W      512
#define KWIN   15
#define PAD    7
#define TH     16                 // output rows per wave
#define NRR    (TH + KWIN - 1)    // 30 input rows per wave
#define STRIP  112                // output cols per wave (frame = 128 cols)
#define NSTRIP 5                  // ceil(512/112): last strip partial (cols 448..511)
#define NWAVES (BATCH * (H / TH) * NSTRIP)   // 5120

static __device__ __forceinline__ float2 min2(float2 a, float2 b) {
    float2 r;
    r.x = fminf(a.x, b.x);
    r.y = fminf(a.y, b.y);
    return r;
}

// Fully fused dark-channel + 15x15 min-pool. ZERO LDS, ZERO barriers.
// Wave = 16 out rows x 112 out cols. Lane owns 2 frame cols (frame = strip
// cols -8..+119). Per input row: 3 independent b64 loads -> channel-min ->
// h-min via 5 shuffles (pair-min p; 7-wide sliding min q7 = min(t4, su(t4,3))
// with t4 = 4-wide doubling; edge cols patched from neighbor lanes' d).
// Vertical 15-min via van Herk with P[15] in registers (forces ~50+ VGPR,
// breaking the allocator's 28-VGPR load-serialization regime seen in R8;
// stays below the ~88-live spill cliff seen in R4/R5). No __launch_bounds__.
__global__ void dcp_fused6(const float* __restrict__ I, float* __restrict__ out) {
    const int wid = blockIdx.x * 4 + (threadIdx.x >> 6);
    const int L   = threadIdx.x & 63;
    const int s   = wid % NSTRIP;
    const int rb  = (wid / NSTRIP) % (H / TH);
    const int b   = wid / (NSTRIP * (H / TH));
    const int y0  = rb * TH;
    const int f   = s * STRIP - 8 + 2 * L;          // frame col (even; may be <0 or >=W)
    const int cl  = min(max(f, 0), W - 2);          // clamped, alignment-preserving
    const bool cv = (f >= 0) && (f < W);            // cols (f,f+1) inside image
    const bool st = (L >= 4) && (L <= 59) && (f < W);  // this lane stores output

    const float* base = I + (size_t)b * CH * H * W + cl;
    float* outb = out + (size_t)b * H * W;

    // h-min of dark row y0-PAD+i at this lane's 2 frame cols
    auto hrow = [&](int i) -> float2 {
        const int y = y0 - PAD + i;
        float2 wv;
        if (y >= 0 && y < H) {                      // wave-uniform branch
            const float* p = base + (size_t)y * W;
            const float2 A = *(const float2*)(p);
            const float2 Bv = *(const float2*)(p + (size_t)H * W);
            const float2 Cv = *(const float2*)(p + (size_t)2 * H * W);
            float2 d = min2(min2(A, Bv), Cv);
            if (!cv) { d.x = INFINITY; d.y = INFINITY; }   // image edge -> +inf pad
            const float pm = fminf(d.x, d.y);              // pair min (cols f,f+1)
            const float t2 = fminf(pm, __shfl_down(pm, 1));
            const float t4 = fminf(t2, __shfl_down(t2, 2)); // min p[K..K+3]
            const float q7 = fminf(t4, __shfl_up(t4, 3));   // min p[K-3..K+3] (cols f-6..f+7)
            wv.x = fminf(q7, __shfl_up(d.y, 4));            // + col f-7
            wv.y = fminf(q7, __shfl_down(d.x, 4));          // + col f+8
        } else {
            wv.x = INFINITY; wv.y = INFINITY;               // torch -inf max-pool pad
        }
        return wv;
    };

    // Vertical van Herk: P[j] = min(hm rows 15..15+j); then stream rows 14..0.
    float2 P[KWIN];
    P[0] = hrow(KWIN);
    #pragma unroll
    for (int j = 1; j < KWIN; ++j) P[j] = min2(P[j - 1], hrow(KWIN + j));
    if (st) *(float2*)(outb + (size_t)(y0 + 15) * W + f) = P[KWIN - 1];

    float2 U = hrow(14);
    if (st) *(float2*)(outb + (size_t)(y0 + 14) * W + f) = min2(U, P[13]);
    #pragma unroll
    for (int r = 13; r >= 1; --r) {
        U = min2(U, hrow(r));
        if (st) *(float2*)(outb + (size_t)(y0 + r) * W + f) = min2(U, P[r - 1]);
    }
    U = min2(U, hrow(0));
    if (st) *(float2*)(outb + (size_t)y0 * W + f) = U;
}

extern "C" void kernel_launch(void* const* d_in, const int* in_sizes, int n_in,
                              void* d_out, int out_size, void* d_ws, size_t ws_size,
                              hipStream_t stream) {
    const float* I = (const float*)d_in[0];
    // d_in[1] is k == 15, hard-coded (KWIN/PAD)
    float* out = (float*)d_out;
    dcp_fused6<<<dim3(NWAVES / 4), dim3(256), 0, stream>>>(I, out);
}

// Round 10
// 161.948 us; speedup vs baseline: 1.0285x; 1.0285x over previous
//
#include <hip/hip_runtime.h>
#include <math.h>

#define BATCH  32
#define CH     3
#define H      512
#define W      512
#define KWIN   15
#define PAD    7
#define TH     16                 // output rows per wave
#define NRR    (TH + KWIN - 1)    // 30 input rows per wave
#define STRIP  112                // output cols per wave (frame = 128 cols)
#define NSTRIP 5                  // ceil(512/112): last strip partial
#define NWAVES (BATCH * (H / TH) * NSTRIP)   // 5120

static __device__ __forceinline__ float2 min2(float2 a, float2 b) {
    float2 r;
    r.x = fminf(a.x, b.x);
    r.y = fminf(a.y, b.y);
    return r;
}

// Fully fused dark-channel + 15x15 min-pool. Zero LDS, zero barriers.
// Wave = 16 out rows x 112 out cols; lane owns 2 frame cols.
// vs R9: loads are UNCONDITIONAL (clamped row; +inf fixup by select after the
// load) and explicitly software-pipelined at distance 2 over a flat 30-row
// sequence, so >=2 rows (3 KB/wave) of loads are in flight by construction.
// This compiler sinks branch-guarded loads to their use (R8: chose VGPR=28
// with a free budget -> serialized); branch-free + pipelined defeats that.
// No __launch_bounds__ (R3/R5 pathologies).
__global__ void dcp_fused7(const float* __restrict__ I, float* __restrict__ out) {
    const int wid = blockIdx.x * 4 + (threadIdx.x >> 6);
    const int L   = threadIdx.x & 63;
    const int s   = wid % NSTRIP;
    const int rb  = (wid / NSTRIP) % (H / TH);
    const int b   = wid / (NSTRIP * (H / TH));
    const int y0  = rb * TH;
    const int f   = s * STRIP - 8 + 2 * L;            // frame col (even)
    const int cl  = min(max(f, 0), W - 2);            // clamped, keeps 8B alignment
    const bool cv = (f >= 0) && (f < W);
    const bool st = (L >= 4) && (L <= 59) && (f < W); // lane stores output

    const float* base = I + (size_t)b * CH * H * W + cl;
    float* outb = out + (size_t)b * H * W;

    // flat step s -> h-min row index: 15..29 (P-build), then 14..0 (U-stream)
    auto seqrow = [](int q) { return q < KWIN ? KWIN + q : 29 - q; };

    auto loadrow = [&](int i, float2& A, float2& B, float2& C) {
        const int yc = min(max(y0 - PAD + i, 0), H - 1);
        const float* p = base + (size_t)yc * W;
        A = *(const float2*)(p);
        B = *(const float2*)(p + (size_t)H * W);
        C = *(const float2*)(p + (size_t)2 * H * W);
    };

    auto hcompute = [&](int i, float2 A, float2 B, float2 C) -> float2 {
        const int y = y0 - PAD + i;
        float2 d = min2(min2(A, B), C);
        const bool pad = (y < 0) || (y >= H) || !cv;
        d.x = pad ? INFINITY : d.x;                   // select, not branch
        d.y = pad ? INFINITY : d.y;
        const float pm = fminf(d.x, d.y);             // pair min (cols f,f+1)
        const float t2 = fminf(pm, __shfl_down(pm, 1));
        const float t4 = fminf(t2, __shfl_down(t2, 2));
        const float q7 = fminf(t4, __shfl_up(t4, 3)); // cols f-6..f+7
        float2 wv;
        wv.x = fminf(q7, __shfl_up(d.y, 4));          // + col f-7
        wv.y = fminf(q7, __shfl_down(d.x, 4));        // + col f+8
        return wv;
    };

    float2 Ab[3], Bb[3], Cb[3];
    loadrow(seqrow(0), Ab[0], Bb[0], Cb[0]);
    loadrow(seqrow(1), Ab[1], Bb[1], Cb[1]);

    float2 P[KWIN];
    float2 U;
    #pragma unroll
    for (int q = 0; q < NRR; ++q) {
        if (q + 2 < NRR)
            loadrow(seqrow(q + 2), Ab[(q + 2) % 3], Bb[(q + 2) % 3], Cb[(q + 2) % 3]);
        const float2 h = hcompute(seqrow(q), Ab[q % 3], Bb[q % 3], Cb[q % 3]);

        if (q == 0) {
            P[0] = h;
        } else if (q < KWIN) {
            P[q] = min2(P[q - 1], h);                 // P[q] = min(rows 15..15+q)
            if (q == KWIN - 1 && st)
                *(float2*)(outb + (size_t)(y0 + 15) * W + f) = P[KWIN - 1];
        } else if (q == KWIN) {                       // row 14
            U = h;
            if (st) *(float2*)(outb + (size_t)(y0 + 14) * W + f) = min2(U, P[13]);
        } else if (q < NRR - 1) {                     // rows 13..1
            const int r = 29 - q;
            U = min2(U, h);
            if (st) *(float2*)(outb + (size_t)(y0 + r) * W + f) = min2(U, P[r - 1]);
        } else {                                      // row 0
            U = min2(U, h);
            if (st) *(float2*)(outb + (size_t)y0 * W + f) = U;
        }
    }
}

extern "C" void kernel_launch(void* const* d_in, const int* in_sizes, int n_in,
                              void* d_out, int out_size, void* d_ws, size_t ws_size,
                              hipStream_t stream) {
    const float* I = (const float*)d_in[0];
    // d_in[1] is k == 15, hard-coded (KWIN/PAD)
    float* out = (float*)d_out;
    dcp_fused7<<<dim3(NWAVES / 4), dim3(256), 0, stream>>>(I, out);
}